// Round 1
// baseline (1958.056 us; speedup 1.0000x reference)
//
#include <hip/hip_runtime.h>
#include <math.h>

#define NQ 14
#define NL 6
#define SIZE 16384      // 2^14 amplitudes
#define HALF 8192
#define NTHREADS 256
#define NGATES (NL * NQ) // 84 Rot gates

// One block per batch element. State vector lives in LDS as SoA (re[], im[]).
// Wire w maps to bit position (13 - w) of the flat index (MSB-first, JAX
// tensor axis order). <Z0> = sum over bit13==0 minus bit13==1.
__global__ __launch_bounds__(NTHREADS) void qsim_kernel(
    const float* __restrict__ x,       // (B, 14)
    const float* __restrict__ wts,     // (6, 14, 3)
    float* __restrict__ out)           // (B,)
{
    extern __shared__ float lds[];
    float* re = lds;                 // [SIZE]
    float* im = lds + SIZE;          // [SIZE]
    float* gm = lds + 2 * SIZE;      // [NGATES*8] Rot matrices (complex 2x2)

    const int tid = threadIdx.x;
    const int b = blockIdx.x;

    // ---- precompute Rot matrices (batch-shared weights) ----
    // Rot(phi,theta,omega) = RZ(omega) RY(theta) RZ(phi):
    //   m00 =  c * e^{-i(phi+omega)/2}
    //   m01 = -s * e^{+i(phi-omega)/2}
    //   m10 =  s * e^{-i(phi-omega)/2}
    //   m11 =  c * e^{+i(phi+omega)/2}
    for (int g = tid; g < NGATES; g += NTHREADS) {
        float phi = wts[g * 3 + 0], th = wts[g * 3 + 1], om = wts[g * 3 + 2];
        float c = cosf(0.5f * th), s = sinf(0.5f * th);
        float a = 0.5f * (phi + om), bb = 0.5f * (phi - om);
        float ca = cosf(a), sa = sinf(a);
        float cb = cosf(bb), sb = sinf(bb);
        gm[g * 8 + 0] = c * ca;  gm[g * 8 + 1] = -c * sa;   // m00
        gm[g * 8 + 2] = -s * cb; gm[g * 8 + 3] = -s * sb;   // m01
        gm[g * 8 + 4] = s * cb;  gm[g * 8 + 5] = -s * sb;   // m10
        gm[g * 8 + 6] = c * ca;  gm[g * 8 + 7] = c * sa;    // m11
    }
    // ---- init |0...0> ----
    for (int i = tid; i < SIZE; i += NTHREADS) {
        re[i] = (i == 0) ? 1.0f : 0.0f;
        im[i] = 0.0f;
    }
    __syncthreads();

    // ---- angle encoding: RX(x[b][q]) on wire q ----
    for (int q = 0; q < NQ; ++q) {
        float t = x[b * NQ + q];
        float c = cosf(0.5f * t), s = sinf(0.5f * t);
        int st = 1 << (13 - q);
        for (int k = tid; k < HALF; k += NTHREADS) {
            int lo = ((k & ~(st - 1)) << 1) | (k & (st - 1));
            int hi = lo | st;
            float r0 = re[lo], i0 = im[lo], r1 = re[hi], i1 = im[hi];
            // [[c, -i s], [-i s, c]]
            re[lo] = c * r0 + s * i1;
            im[lo] = c * i0 - s * r1;
            re[hi] = s * i0 + c * r1;
            im[hi] = -s * r0 + c * i1;
        }
        __syncthreads();
    }

    // ---- StronglyEntanglingLayers ----
    for (int l = 0; l < NL; ++l) {
        // Rot on every wire
        for (int q = 0; q < NQ; ++q) {
            const float* m = &gm[(l * NQ + q) * 8];
            float m00r = m[0], m00i = m[1], m01r = m[2], m01i = m[3];
            float m10r = m[4], m10i = m[5], m11r = m[6], m11i = m[7];
            int st = 1 << (13 - q);
            for (int k = tid; k < HALF; k += NTHREADS) {
                int lo = ((k & ~(st - 1)) << 1) | (k & (st - 1));
                int hi = lo | st;
                float r0 = re[lo], i0 = im[lo], r1 = re[hi], i1 = im[hi];
                re[lo] = m00r * r0 - m00i * i0 + m01r * r1 - m01i * i1;
                im[lo] = m00r * i0 + m00i * r0 + m01r * i1 + m01i * r1;
                re[hi] = m10r * r0 - m10i * i0 + m11r * r1 - m11i * i1;
                im[hi] = m10r * i0 + m10i * r0 + m11r * i1 + m11i * r1;
            }
            __syncthreads();
        }
        // CNOT ring with range r
        int rr = (l % (NQ - 1)) + 1;
        for (int cq = 0; cq < NQ; ++cq) {
            int tq = (cq + rr) % NQ;
            int pc = 13 - cq, pt = 13 - tq;
            int p1 = (pc > pt) ? pc : pt;
            int p0 = (pc > pt) ? pt : pc;
            int gap = p1 - 1 - p0;  // bits between the two removed positions
            for (int k = tid; k < SIZE / 4; k += NTHREADS) {
                int lowpart = k & ((1 << p0) - 1);
                int rest = k >> p0;
                int midpart = rest & ((1 << gap) - 1);
                int hipart = rest >> gap;
                int idx = lowpart | (midpart << (p0 + 1)) | (hipart << (p1 + 1));
                idx |= (1 << pc);            // control bit = 1, target bit = 0
                int jdx = idx | (1 << pt);   // target bit = 1
                float tr = re[idx], ti = im[idx];
                re[idx] = re[jdx]; im[idx] = im[jdx];
                re[jdx] = tr;      im[jdx] = ti;
            }
            __syncthreads();
        }
    }

    // ---- <Z0> reduction: +|amp|^2 if bit13==0 else - ----
    float acc = 0.0f;
    for (int i = tid; i < SIZE; i += NTHREADS) {
        float v = re[i] * re[i] + im[i] * im[i];
        acc += (i & HALF) ? -v : v;
    }
    // wave (64-lane) reduction
    #pragma unroll
    for (int off = 32; off > 0; off >>= 1)
        acc += __shfl_down(acc, off, 64);
    __syncthreads();  // gm no longer needed; reuse for cross-wave sums
    if ((tid & 63) == 0) gm[tid >> 6] = acc;
    __syncthreads();
    if (tid == 0) out[b] = gm[0] + gm[1] + gm[2] + gm[3];
}

extern "C" void kernel_launch(void* const* d_in, const int* in_sizes, int n_in,
                              void* d_out, int out_size, void* d_ws, size_t ws_size,
                              hipStream_t stream) {
    const float* x = (const float*)d_in[0];     // (1024, 14) float32
    const float* w = (const float*)d_in[1];     // (6, 14, 3) float32
    float* out = (float*)d_out;                 // (1024,) float32

    size_t smem = (size_t)(2 * SIZE + NGATES * 8) * sizeof(float); // ~133.6 KB
    qsim_kernel<<<out_size, NTHREADS, smem, stream>>>(x, w, out);
}